// Round 1
// baseline (174.058 us; speedup 1.0000x reference)
//
#include <hip/hip_runtime.h>

// HONU order-3: out[b] = sum_{i<=j<=k} w[idx(i,j,k)] * xf[b,i]*xf[b,j]*xf[b,k]
// xf = [1, x[b,0..125]]  (127 features). Combination index is closed-form
// (lexicographic combinations_with_replacement), so comb_idx input is unused.

#define N_FEAT   127
#define C_TOT    349504      // Te(127) = 127*128*129/6
#define IN_LEN   126
#define TILE     64          // batch rows per block
#define NTILES   4           // 256 / 64
#define NTASKS   1072        // sum_j ceil((j+1)/8)
#define IBLK     8

__device__ __forceinline__ int F_off(int i) {
    // # combos with first index < i
    int m = N_FEAT - i;
    return C_TOT - m * (m + 1) * (m + 2) / 6;
}

__global__ __launch_bounds__(256, 4) void honu_kernel(
    const float* __restrict__ x, const float* __restrict__ w,
    float* __restrict__ out, int* __restrict__ counters)
{
    __shared__ float xT[N_FEAT * TILE];   // xT[c*64 + r] : transposed tile, col 0 = bias
    __shared__ float red[4 * TILE];

    const int tid  = threadIdx.x;
    const int lane = tid & 63;
    const int tile = blockIdx.y;

    // ---- stage x tile (transposed, bias prepended) ----
    for (int e = tid; e < N_FEAT * TILE; e += 256) {
        const int c = e >> 6, r = e & 63;
        xT[e] = (c == 0) ? 1.0f : x[(tile * TILE + r) * IN_LEN + (c - 1)];
    }
    __syncthreads();

    float acc = 0.0f;
    int* counter = counters + tile;

    for (;;) {
        // wave grabs next task (tasks are pre-sorted large->small: greedy balance)
        int t0 = 0;
        if (lane == 0) t0 = atomicAdd(counter, 1);
        const int t = __builtin_amdgcn_readfirstlane(t0);
        if (t >= NTASKS) break;

        // decode t -> (j, i0): per-j task count = (j>>3)+1
        int j = 0, rem = t;
        for (;;) {
            const int cnt = (j >> 3) + 1;
            if (rem < cnt) break;
            rem -= cnt; ++j;
        }
        const int i0 = rem << 3;
        const int L  = N_FEAT - j;       // k runs j..126, weights contiguous

        // scalar weight bases for the 8 i-streams
        int base[IBLK];
        #pragma unroll
        for (int tt = 0; tt < IBLK; ++tt) {
            const int i = i0 + tt;
            int b = 0;
            if (i <= j) {
                const int Gij = (j - i) * N_FEAT - ((i + j - 1) * (j - i)) / 2;
                b = F_off(i) + Gij;
            }
            base[tt] = __builtin_amdgcn_readfirstlane(b);
        }

        float d[IBLK] = {0.f, 0.f, 0.f, 0.f, 0.f, 0.f, 0.f, 0.f};
        const float* xcol = &xT[j * TILE + lane];

        #pragma unroll 4
        for (int kk = 0; kk < L; ++kk) {
            const float xv = xcol[kk * TILE];       // lane-consecutive: conflict-free
            #pragma unroll
            for (int tt = 0; tt < IBLK; ++tt)
                d[tt] = fmaf(w[base[tt] + kk], xv, d[tt]);   // s_load + v_fmac(s,v)
        }

        const float xj = xT[j * TILE + lane];
        #pragma unroll
        for (int tt = 0; tt < IBLK; ++tt) {
            const int i = i0 + tt;
            const float xi = (i <= j) ? xT[i * TILE + lane] : 0.0f;
            acc = fmaf(xi * xj, d[tt], acc);
        }
    }

    // ---- block reduce: 4 waves cover same 64 rows ----
    red[(tid >> 6) * TILE + lane] = acc;
    __syncthreads();
    if (tid < TILE) {
        const float s = red[tid] + red[TILE + tid] + red[2 * TILE + tid] + red[3 * TILE + tid];
        atomicAdd(&out[tile * TILE + tid], s);
    }
}

extern "C" void kernel_launch(void* const* d_in, const int* in_sizes, int n_in,
                              void* d_out, int out_size, void* d_ws, size_t ws_size,
                              hipStream_t stream)
{
    const float* x = (const float*)d_in[0];
    const float* w = (const float*)d_in[1];
    // d_in[2] (comb_idx) intentionally unused: index table is closed-form.
    float* out    = (float*)d_out;
    int* counters = (int*)d_ws;

    hipMemsetAsync(out, 0, 256 * sizeof(float), stream);
    hipMemsetAsync(counters, 0, NTILES * sizeof(int), stream);

    honu_kernel<<<dim3(256, NTILES), 256, 0, stream>>>(x, w, out, counters);
}

// Round 2
// 79.330 us; speedup vs baseline: 2.1941x; 2.1941x over previous
//
#include <hip/hip_runtime.h>

// HONU order-3: out[b] = sum_{i<=j<=k} w[idx(i,j,k)] * xf[b,i]*xf[b,j]*xf[b,k]
// xf = [1, x[b,:]] (127 features). idx is closed-form (lexicographic
// combinations_with_replacement) -> comb_idx input is never read.
//
// R2 design: NO atomics (static round-robin task assignment), inner loop is
// pure LDS+FMA (weights staged per-task into LDS, x tile staged once).
// Task = (j, block of 16 i-streams); 4 waves split the k-range.

#define N_FEAT 127
#define C_TOT  349504        // Te(127)
#define IN_LEN 126
#define TILE   64            // batch rows per block
#define NTILES 4             // 256/64
#define NB     192           // blocks per row-tile (768 total = 3/CU, one round)
#define NI     16            // i-streams per task
#define NTASK  568           // sum_j ceil((j+1)/16)
#define XPAD   131           // xS row stride (odd -> 2-way bank alias = free)
#define WROW   128           // wbuf row stride (max padded k-length)

__device__ __forceinline__ int Foff(int i) {
    const int m = N_FEAT - i;
    return C_TOT - m * (m + 1) * (m + 2) / 6;
}
__device__ __forceinline__ int baseij(int i, int j) {
    return Foff(i) + (j - i) * N_FEAT - ((i + j - 1) * (j - i)) / 2;
}

__global__ __launch_bounds__(256, 3) void honu2(
    const float* __restrict__ x, const float* __restrict__ w,
    float* __restrict__ out)
{
    __shared__ float xS[TILE * XPAD];      // [row][feat], col0 = bias, cols 127..130 = 0
    __shared__ float wbuf[NI * WROW];      // [i-stream][k-k0], zero-padded
    __shared__ float red[4 * TILE];

    const int tid  = threadIdx.x;
    const int lane = tid & 63;
    const int wv   = tid >> 6;
    const int tile = blockIdx.y;
    const int g    = blockIdx.x;

    // ---- stage x tile (linear coalesced copy; compiler magic-div by 126) ----
    const float* xsrc = x + (size_t)tile * TILE * IN_LEN;
    for (int e = tid; e < TILE * IN_LEN; e += 256) {
        const int r = e / IN_LEN;
        const int c = e - r * IN_LEN;
        xS[r * XPAD + c + 1] = xsrc[e];
    }
    for (int r = tid; r < TILE; r += 256) xS[r * XPAD] = 1.0f;     // bias feature
    for (int e = tid; e < TILE * (XPAD - N_FEAT); e += 256) {       // zero pad cols
        const int r = e >> 2, c = e & 3;
        xS[r * XPAD + N_FEAT + c] = 0.0f;
    }

    float acc = 0.0f;

    // ---- static task walk: t = g, g+NB, ...; incremental (j,i0) decode ----
    int t = g, jcur = 0, cum = 0;
    while (t < NTASK) {
        int nt_j = (jcur + 1 + NI - 1) >> 4;          // tasks at jcur
        while (cum + nt_j <= t) { cum += nt_j; ++jcur; nt_j = (jcur + 16) >> 4; }
        const int j  = jcur;
        const int i0 = (t - cum) << 4;
        const int k0 = j & ~3;
        const int L4 = (N_FEAT - k0 + 3) & ~3;        // padded k-length (<=128)
        const int nI = min(NI, j + 1 - i0);

        __syncthreads();                               // wbuf readers done
        // ---- stage wbuf[ip][kk]: coalesced in kk, zero outside valid range ----
        {
            const int kk = tid & 127;
            const int i2 = tid >> 7;                   // 0..1
            #pragma unroll
            for (int p = 0; p < NI / 2; ++p) {
                const int ip = i2 + p * 2;
                const int k  = k0 + kk;
                float v = 0.0f;
                if (ip < nI && k >= j && k < N_FEAT)
                    v = w[baseij(i0 + ip, j) + (k - j)];
                wbuf[ip * WROW + kk] = v;
            }
        }
        __syncthreads();

        // ---- compute: wave wv takes k-blocks kb = wv, wv+4, ... ----
        float d[NI];
        #pragma unroll
        for (int q = 0; q < NI; ++q) d[q] = 0.0f;

        const int KB = L4 >> 2;
        const float* xrow = &xS[lane * XPAD];
        for (int kb = wv; kb < KB; kb += 4) {
            const int kbase = k0 + (kb << 2);
            const float x0 = xrow[kbase + 0];
            const float x1 = xrow[kbase + 1];
            const float x2 = xrow[kbase + 2];
            const float x3 = xrow[kbase + 3];
            #pragma unroll
            for (int q = 0; q < NI; ++q) {
                const float4 w4 = *(const float4*)&wbuf[q * WROW + (kb << 2)];
                d[q] = fmaf(w4.x, x0, d[q]);
                d[q] = fmaf(w4.y, x1, d[q]);
                d[q] = fmaf(w4.z, x2, d[q]);
                d[q] = fmaf(w4.w, x3, d[q]);
            }
        }

        // ---- apply xf_i * xf_j (d[q]=0 for q>=nI; xS pad is 0 -> safe) ----
        const float xj = xrow[j];
        #pragma unroll
        for (int q = 0; q < NI; ++q) {
            const float xi = xrow[i0 + q];
            acc = fmaf(xi * xj, d[q], acc);
        }
        t += NB;
    }

    // ---- block reduce (4 waves cover same 64 rows), one atomic per row ----
    red[wv * TILE + lane] = acc;
    __syncthreads();
    if (tid < TILE) {
        const float s = red[tid] + red[TILE + tid] + red[2 * TILE + tid] + red[3 * TILE + tid];
        atomicAdd(&out[tile * TILE + tid], s);
    }
}

extern "C" void kernel_launch(void* const* d_in, const int* in_sizes, int n_in,
                              void* d_out, int out_size, void* d_ws, size_t ws_size,
                              hipStream_t stream)
{
    const float* x = (const float*)d_in[0];
    const float* w = (const float*)d_in[1];
    // d_in[2] (comb_idx) unused: index table is closed-form.
    float* out = (float*)d_out;

    hipMemsetAsync(out, 0, 256 * sizeof(float), stream);
    honu2<<<dim3(NB, NTILES), 256, 0, stream>>>(x, w, out);
}